// Round 9
// baseline (218.782 us; speedup 1.0000x reference)
//
#include <hip/hip_runtime.h>
#include <hip/hip_bf16.h>
#include <stdint.h>

#define LN_EPS 1e-5f

typedef __attribute__((ext_vector_type(8))) short bf16x8;
typedef __attribute__((ext_vector_type(16))) float f32x16;
typedef __attribute__((ext_vector_type(4))) short short4v;

__device__ __forceinline__ short f2bf(float x) {
    union { __hip_bfloat16 b; short s; } u;
    u.b = __float2bfloat16(x);   // RNE
    return u.s;
}
__device__ __forceinline__ float lo_bf(unsigned v) {
    union { unsigned u; float f; } c; c.u = v << 16; return c.f;
}
__device__ __forceinline__ float hi_bf(unsigned v) {
    union { unsigned u; float f; } c; c.u = v & 0xFFFF0000u; return c.f;
}
__device__ __forceinline__ float sigm(float x) { return 1.f / (1.f + __expf(-x)); }
__device__ __forceinline__ float tanh_f(float x) {
    x = fminf(15.f, fmaxf(-15.f, x));
    float e = __expf(2.f * x);
    return (e - 1.f) / (e + 1.f);
}

// ---------------------------------------------------------------------------
// Fused pack: [x|h] -> Acat bf16[4096][2048], [w_ih|w_hh] -> Wcat bf16[4096][2048]
// ---------------------------------------------------------------------------
__global__ __launch_bounds__(256)
void pack_all_bf16(const float* __restrict__ x, const float* __restrict__ h,
                   const float* __restrict__ wih, const float* __restrict__ whh,
                   short* __restrict__ Acat, short* __restrict__ Wcat)
{
    const int total = 4 * 1024 * 1024;           // float4 quads (A: 2M, W: 2M)
    for (int q = blockIdx.x * blockDim.x + threadIdx.x; q < total;
         q += gridDim.x * blockDim.x) {
        const int  qq  = q & (2 * 1024 * 1024 - 1);
        const bool isW = q >= 2 * 1024 * 1024;
        const float* s0 = isW ? wih : x;
        const float* s1 = isW ? whh : h;
        short* dst = isW ? Wcat : Acat;
        const long n = (long)qq << 2;            // element index
        const long r = n >> 11;                  // row (C=2048)
        const int  k = (int)(n & 2047);
        const float* src = (k < 1024) ? (s0 + (r << 10) + k)
                                      : (s1 + (r << 10) + (k - 1024));
        float4 v = *(const float4*)src;
        short4v o;
        o.x = f2bf(v.x); o.y = f2bf(v.y); o.z = f2bf(v.z); o.w = f2bf(v.w);
        *(short4v*)(dst + n) = o;
    }
}

// ---------------------------------------------------------------------------
// 256x256 8-phase GEMM, 32x32x16 MFMA edition.
// T2 swizzle = 3-bit row XOR: phys = logical ^ ((row&7)<<4), row = logical>>7.
// (verified round 6: SQ_LDS_BANK_CONFLICT == 0)
//
// Wave tile 128x64 = 4m x 2n subtiles of 32x32; BK=64 = 4 ks-slices of K=16.
// Phase->work: P1=(m01,ks01) P2=(m01,ks23) P3=(m23,ks01) P4=(m23,ks23).
// ds_reads/phase: 8/8/8/0 (A-hi all-ks read at P3; B both-ks held in regs).
// Read-completion: A last-read P3, B last-read P2 -> staging schedule and
// race audit identical to the verified round-3/6 kernel:
//   P1: a1(t+1) [other buf]; P3: b0(t+2); P4: b1(t+2)+a0(t+2) then vmcnt(6)
//   (completes the 8 oldest = all 4 halves of tile t+1; leaves 6 in flight).
// ---------------------------------------------------------------------------
#define SWZ(x) ((x) ^ (((((x) >> 7) & 7)) << 4))

__device__ __forceinline__ void stage_half(const short* __restrict__ G, int rowBase,
                                           int t, char* halfRegion, int tid)
{
    // linear LDS dest (wave-uniform base + lane*16); inverse-swizzled global src
    #pragma unroll
    for (int j = 0; j < 2; ++j) {
        const int p   = j * 8192 + tid * 16;     // physical byte in 16KB half
        const int l   = SWZ(p);                  // logical byte (involution)
        const int row = l >> 7;                  // 128B row stride
        const int kel = (l & 127) >> 1;
        const short* src = G + (size_t)(rowBase + row) * 2048 + t * 64 + kel;
        __builtin_amdgcn_global_load_lds(
            (const __attribute__((address_space(1))) void*)src,
            (__attribute__((address_space(3))) void*)(halfRegion + j * 8192 + ((tid >> 6) << 10)),
            16, 0, 0);
    }
}

__device__ __forceinline__ bf16x8 ldsRead(const char* region, int logical)
{
    return *(const bf16x8*)(region + SWZ(logical));
}

#define BARR()      __builtin_amdgcn_s_barrier()
#define WAIT_LGKM() do { asm volatile("s_waitcnt lgkmcnt(0)" ::: "memory"); \
                         __builtin_amdgcn_sched_barrier(0); } while (0)
#define WAIT_VM6()  asm volatile("s_waitcnt vmcnt(6)" ::: "memory")
#define WAIT_VM0()  asm volatile("s_waitcnt vmcnt(0)" ::: "memory")
#define MFMA32(a, b, c) __builtin_amdgcn_mfma_f32_32x32x16_bf16((a), (b), (c), 0, 0, 0)

__global__ __launch_bounds__(512, 2)
void gemm256_8p(const short* __restrict__ A, const short* __restrict__ B,
                unsigned short* __restrict__ C)
{
    __shared__ __align__(1024) char smem[131072];  // [2 buf][A 32KB | B 32KB]
    const int tid  = threadIdx.x;
    const int lane = tid & 63;
    const int wave = tid >> 6;
    const int wr = wave >> 2;          // 0..1  (128-row stripe)
    const int wc = wave & 3;           // 0..3  (64-col stripe)
    const int bx = blockIdx.x & 15, by = blockIdx.x >> 4;
    const int brow = by * 256, bcol = bx * 256;
    const int NT = 32;                 // K=2048 / BK=64

    // per-lane logical byte bases: row = stripe + (lane&31), kbyte = (lane>>5)*16
    const int aBase = (wr * 128 + (lane & 31)) * 128 + ((lane >> 5) << 4);
    const int bBase = (wc * 64  + (lane & 31)) * 128 + ((lane >> 5) << 4);

    f32x16 acc[4][2] = {};
    bf16x8 aF[2][2];      // A-lo frags (current ks-pair)
    bf16x8 aH[2][4];      // A-hi frags (all ks, read at P3)
    bf16x8 b01[2][2];     // B frags ks0,1
    bf16x8 b23[2][2];     // B frags ks2,3

    char* Areg0 = smem;             char* Breg0 = smem + 32768;
    char* Areg1 = smem + 65536;     char* Breg1 = smem + 65536 + 32768;

    // ---- prologue: tile0 fully + {b0,b1,a0}(1); vmcnt(6) leaves those 3 in flight
    stage_half(A, brow +   0, 0, Areg0 +     0, tid);   // a0(0)
    stage_half(A, brow + 128, 0, Areg0 + 16384, tid);   // a1(0)
    stage_half(B, bcol +   0, 0, Breg0 +     0, tid);   // b0(0)
    stage_half(B, bcol + 128, 0, Breg0 + 16384, tid);   // b1(0)
    stage_half(B, bcol +   0, 1, Breg1 +     0, tid);   // b0(1)
    stage_half(B, bcol + 128, 1, Breg1 + 16384, tid);   // b1(1)
    stage_half(A, brow +   0, 1, Areg1 +     0, tid);   // a0(1)
    WAIT_VM6();                                          // tile0 complete
    BARR();

    for (int it = 0; it < 16; ++it) {
        const int t0 = it * 2;
        #pragma unroll
        for (int hb = 0; hb < 2; ++hb) {
            const int t = t0 + hb;
            const char* Ar = hb ? Areg1 : Areg0;   // compute buffer = t&1 = hb
            const char* Br = hb ? Breg1 : Breg0;
            char* ArN = hb ? Areg0 : Areg1;        // buffer of tile t+1
            char* AwC = hb ? Areg1 : Areg0;        // buffer of tile t+2 (= current)
            char* BwC = hb ? Breg1 : Breg0;

            // ---- P1: (m01, ks01) — 8 ds_reads, stage a1(t+1) [other buf]
            #pragma unroll
            for (int m = 0; m < 2; ++m)
                #pragma unroll
                for (int k = 0; k < 2; ++k)
                    aF[m][k] = ldsRead(Ar, aBase + m * 4096 + k * 32);
            #pragma unroll
            for (int n = 0; n < 2; ++n)
                #pragma unroll
                for (int k = 0; k < 2; ++k)
                    b01[n][k] = ldsRead(Br, bBase + n * 4096 + k * 32);
            if (t + 1 < NT) stage_half(A, brow + 128, t + 1, ArN + 16384, tid);
            BARR(); WAIT_LGKM();
            __builtin_amdgcn_s_setprio(1);
            #pragma unroll
            for (int k = 0; k < 2; ++k)
                #pragma unroll
                for (int m = 0; m < 2; ++m)
                    #pragma unroll
                    for (int n = 0; n < 2; ++n)
                        acc[m][n] = MFMA32(aF[m][k], b01[n][k], acc[m][n]);
            __builtin_amdgcn_s_setprio(0);
            BARR();

            // ---- P2: (m01, ks23) — 8 ds_reads, NO stage
            #pragma unroll
            for (int m = 0; m < 2; ++m)
                #pragma unroll
                for (int k = 0; k < 2; ++k)
                    aF[m][k] = ldsRead(Ar, aBase + m * 4096 + (2 + k) * 32);
            #pragma unroll
            for (int n = 0; n < 2; ++n)
                #pragma unroll
                for (int k = 0; k < 2; ++k)
                    b23[n][k] = ldsRead(Br, bBase + n * 4096 + (2 + k) * 32);
            BARR(); WAIT_LGKM();
            __builtin_amdgcn_s_setprio(1);
            #pragma unroll
            for (int k = 0; k < 2; ++k)
                #pragma unroll
                for (int m = 0; m < 2; ++m)
                    #pragma unroll
                    for (int n = 0; n < 2; ++n)
                        acc[m][n] = MFMA32(aF[m][k], b23[n][k], acc[m][n]);
            __builtin_amdgcn_s_setprio(0);
            BARR();

            // ---- P3: (m23, ks01) — 8 ds_reads (A-hi, ALL ks), stage b0(t+2)
            //      (B reads completed at P2; A last-read is here)
            #pragma unroll
            for (int m = 0; m < 2; ++m)
                #pragma unroll
                for (int k = 0; k < 4; ++k)
                    aH[m][k] = ldsRead(Ar, aBase + (2 + m) * 4096 + k * 32);
            if (t + 2 < NT) stage_half(B, bcol + 0, t + 2, BwC + 0, tid);
            BARR(); WAIT_LGKM();
            __builtin_amdgcn_s_setprio(1);
            #pragma unroll
            for (int k = 0; k < 2; ++k)
                #pragma unroll
                for (int m = 0; m < 2; ++m)
                    #pragma unroll
                    for (int n = 0; n < 2; ++n)
                        acc[2 + m][n] = MFMA32(aH[m][k], b01[n][k], acc[2 + m][n]);
            __builtin_amdgcn_s_setprio(0);
            BARR();

            // ---- P4: (m23, ks23) — 0 ds_reads; stage b1(t+2)+a0(t+2); vmcnt(6)
            if (t + 2 < NT) {
                stage_half(B, bcol + 128, t + 2, BwC + 16384, tid);
                stage_half(A, brow +   0, t + 2, AwC +     0, tid);
                WAIT_VM6();     // completes all 4 halves of tile t+1
            } else {
                WAIT_VM0();     // tail drain (tiles 30,31)
            }
            BARR(); WAIT_LGKM();
            __builtin_amdgcn_s_setprio(1);
            #pragma unroll
            for (int k = 0; k < 2; ++k)
                #pragma unroll
                for (int m = 0; m < 2; ++m)
                    #pragma unroll
                    for (int n = 0; n < 2; ++n)
                        acc[2 + m][n] = MFMA32(aH[m][2 + k], b23[n][k], acc[2 + m][n]);
            __builtin_amdgcn_s_setprio(0);
            BARR();
        }
    }

    // ---- epilogue: 32x32 C/D layout (m74/m101): col=lane&31,
    //      row=(reg&3)+8*(reg>>2)+4*(lane>>5); store bf16
    #pragma unroll
    for (int m = 0; m < 4; ++m)
        #pragma unroll
        for (int n = 0; n < 2; ++n) {
            const int colg  = bcol + wc * 64 + n * 32 + (lane & 31);
            const int rbase = brow + wr * 128 + m * 32 + ((lane >> 5) << 2);
            #pragma unroll
            for (int r = 0; r < 16; ++r) {
                const int row = rbase + (r & 3) + 8 * (r >> 2);
                C[(size_t)row * 4096 + colg] = (unsigned short)f2bf(acc[m][n][r]);
            }
        }
}

// ---------------------------------------------------------------------------
// Per-row LayerNorm over 4096 bf16 gates + LSTM activations. One block per row.
// ---------------------------------------------------------------------------
__global__ __launch_bounds__(256)
void ln_act_kernel(const unsigned short* __restrict__ gates,
                   const float* __restrict__ b_ih, const float* __restrict__ b_hh,
                   const float* __restrict__ gamma, const float* __restrict__ beta,
                   const float* __restrict__ c,
                   float* __restrict__ out_h, float* __restrict__ out_c)
{
    __shared__ float sg[4096];
    __shared__ float rs[4], rq[4];
    const int b = blockIdx.x;
    const int t = threadIdx.x;
    const uint4*  grow = (const uint4*)(gates + ((long)b << 12));  // 512 x 16B
    const float4* bi4  = (const float4*)b_ih;
    const float4* bh4  = (const float4*)b_hh;

    float sum = 0.f, sq = 0.f;
    #pragma unroll
    for (int j = 0; j < 2; ++j) {
        const int q = t + j * 256;           // uint4 index: 8 bf16 = elems [8q,8q+8)
        uint4 u = grow[q];
        float g8[8] = { lo_bf(u.x), hi_bf(u.x), lo_bf(u.y), hi_bf(u.y),
                        lo_bf(u.z), hi_bf(u.z), lo_bf(u.w), hi_bf(u.w) };
        float4 bi0 = bi4[2 * q], bi1 = bi4[2 * q + 1];
        float4 bh0 = bh4[2 * q], bh1 = bh4[2 * q + 1];
        g8[0] += bi0.x + bh0.x;  g8[1] += bi0.y + bh0.y;
        g8[2] += bi0.z + bh0.z;  g8[3] += bi0.w + bh0.w;
        g8[4] += bi1.x + bh1.x;  g8[5] += bi1.y + bh1.y;
        g8[6] += bi1.z + bh1.z;  g8[7] += bi1.w + bh1.w;
        ((float4*)sg)[2 * q]     = { g8[0], g8[1], g8[2], g8[3] };
        ((float4*)sg)[2 * q + 1] = { g8[4], g8[5], g8[6], g8[7] };
        #pragma unroll
        for (int e = 0; e < 8; ++e) { sum += g8[e]; sq += g8[e] * g8[e]; }
    }
    #pragma unroll
    for (int off = 32; off > 0; off >>= 1) {
        sum += __shfl_down(sum, off);
        sq  += __shfl_down(sq, off);
    }
    if ((t & 63) == 0) { rs[t >> 6] = sum; rq[t >> 6] = sq; }
    __syncthreads();
    sum = rs[0] + rs[1] + rs[2] + rs[3];
    sq  = rq[0] + rq[1] + rq[2] + rq[3];
    const float mu   = sum * (1.f / 4096.f);
    const float rstd = rsqrtf(sq * (1.f / 4096.f) - mu * mu + LN_EPS);

    const float4* sg4 = (const float4*)sg;
    const float4* gm4 = (const float4*)gamma;
    const float4* bt4 = (const float4*)beta;
    float4 vi = sg4[t],        vf = sg4[256 + t];
    float4 vg = sg4[512 + t],  vo = sg4[768 + t];
    float4 gi = gm4[t], gf = gm4[256 + t], gg = gm4[512 + t], go = gm4[768 + t];
    float4 zi = bt4[t], zf = bt4[256 + t], zg = bt4[512 + t], zo = bt4[768 + t];
    float4 cc = ((const float4*)c)[((long)b << 8) + t];
    float4 nh, nc;
    {
        float i0, f0, g0, o0;
        #define DO_COMP(X)                                                    \
            i0 = (vi.X - mu) * rstd * gi.X + zi.X;                            \
            f0 = (vf.X - mu) * rstd * gf.X + zf.X;                            \
            g0 = (vg.X - mu) * rstd * gg.X + zg.X;                            \
            o0 = (vo.X - mu) * rstd * go.X + zo.X;                            \
            nc.X = sigm(f0) * cc.X + sigm(i0) * tanh_f(g0);                   \
            nh.X = sigm(o0) * tanh_f(nc.X);
        DO_COMP(x) DO_COMP(y) DO_COMP(z) DO_COMP(w)
        #undef DO_COMP
    }
    ((float4*)out_h)[((long)b << 8) + t] = nh;
    ((float4*)out_c)[((long)b << 8) + t] = nc;
}

// ---------------------------------------------------------------------------
extern "C" void kernel_launch(void* const* d_in, const int* in_sizes, int n_in,
                              void* d_out, int out_size, void* d_ws, size_t ws_size,
                              hipStream_t stream)
{
    const float* x    = (const float*)d_in[0];
    const float* h    = (const float*)d_in[1];
    const float* c    = (const float*)d_in[2];
    const float* w_ih = (const float*)d_in[3];
    const float* w_hh = (const float*)d_in[4];
    const float* b_ih = (const float*)d_in[5];
    const float* b_hh = (const float*)d_in[6];
    const float* gam  = (const float*)d_in[7];
    const float* bet  = (const float*)d_in[8];
    float* out = (float*)d_out;
    (void)in_sizes; (void)n_in; (void)out_size; (void)ws_size;

    const int B = 4096, H = 1024;

    char*  ws    = (char*)d_ws;
    short* Acat  = (short*)ws;                                       // 16 MiB bf16 [4096][2048]
    short* Wcat  = (short*)(ws + (size_t)16 * 1024 * 1024);          // 16 MiB bf16 [4096][2048]
    unsigned short* gates = (unsigned short*)(ws + (size_t)32 * 1024 * 1024); // 32 MiB bf16 [4096][4096]

    pack_all_bf16<<<2048, 256, 0, stream>>>(x, h, w_ih, w_hh, Acat, Wcat);

    gemm256_8p<<<dim3(256), dim3(512), 0, stream>>>(Acat, Wcat, gates);

    ln_act_kernel<<<B, 256, 0, stream>>>(gates, b_ih, b_hh, gam, bet, c,
                                         out, out + (size_t)B * H);
}